// Round 6
// baseline (486.097 us; speedup 1.0000x reference)
//
#include <hip/hip_runtime.h>
#include <hip/hip_fp16.h>

// LMKAN_2D: out(O=256,B=4096) = relu(W(256x128)@x(128x4096) + bias_l)
//           + w_lm * sum_p bilinear4(fp[i,j,:,p])
// K1 transpose: fp[i][j][o][p] f32 -> fpt[i][j][p][o] f16 (132 MiB, L3-fit).
//    Both global sides 1KB/wave contiguous; LDS XOR-swizzled.
// K2 gather (persistent, XCD-phased): 2048 blocks x 128 thr, all co-resident.
//    XCD x = bid&7 owns p-range [8x,8x+8), sweeping ONE p per phase -- the
//    per-p table slab is 2.1 MiB and fits the XCD's 4 MiB L2, converting the
//    previously L3-bound 512 MiB gather into mostly-L2 traffic. Each wave owns
//    8 b-columns, accumulates acc[8][4] in regs across phases, writes a
//    per-(b,XCD) partial (32 MiB) once.
// K3 linear: 128-block GEMM computes relu(Wx+b), folds the 8 partials
//    (coalesced 1KB reads) and writes out.

#define NB 4096
#define ND 128
#define NO 256
#define NP 64
#define NG 65
#define PANEL 16384  // 256*64 elements per (i,j) panel
#define FPT_ELEMS ((size_t)NG * NG * PANEL)          // 69,222,400 halves
#define FPT_BYTES (FPT_ELEMS * 2)                    // 138,444,800 B
#define PART_FLOATS ((size_t)NB * 8 * NO)            // 8,388,608 floats = 32 MiB

typedef float f32x4 __attribute__((ext_vector_type(4)));
union Pack8 { __half h[8]; uint4 v; };

__device__ __forceinline__ int bsearch65(const float* B, float v) {
  int lo = 0, hi = 65;
  while (lo < hi) {
    int m = (lo + hi) >> 1;
    if (B[m] <= v) lo = m + 1; else hi = m;
  }
  int i = lo - 1;
  return i < 0 ? 0 : (i > 63 ? 63 : i);
}

__device__ __forceinline__ void borders_init(float* borders, int t) {
  if (t < 65) {
    float pk = fminf(fmaxf((float)t * (1.0f / 64.0f), 0.0078125f), 0.9921875f);
    borders[t] = 1.41421356237309515f * erfinvf(2.0f * pk - 1.0f);
  }
}

// ---- K1: transpose fp[panel][o][p] f32 -> fpt[panel][p][o] f16 ----
__global__ __launch_bounds__(256) void lmkan_transpose3(
    const float* __restrict__ src, __half* __restrict__ dst) {
  const int panel = blockIdx.x;
  const int t = threadIdx.x;
  __shared__ __half lds[256 * 72];   // [o][72], p XOR-swizzled inside row

  const f32x4* s4 = reinterpret_cast<const f32x4*>(src + (size_t)panel * PANEL);
#pragma unroll
  for (int k = 0; k < 16; ++k) {
    int idx4 = t + 256 * k;          // 1KB contiguous per wave
    f32x4 v = __builtin_nontemporal_load(&s4[idx4]);  // read-once: skip L3
    int o = idx4 >> 4;
    int p0 = (idx4 & 15) * 4;
    int p0s = p0 ^ (((o >> 3) & 15) << 2);
    union { __half2 h2[2]; uint2 u; } pk;
    pk.h2[0] = __floats2half2_rn(v[0], v[1]);
    pk.h2[1] = __floats2half2_rn(v[2], v[3]);
    *reinterpret_cast<uint2*>(&lds[o * 72 + p0s]) = pk.u;
  }
  __syncthreads();

  const int l = t & 63, w = t >> 6;
  const int o0 = (l & 31) * 8;
  const int swz = (l & 15) << 2;
#pragma unroll
  for (int ss = 0; ss < 8; ++ss) {
    int p = ss * 8 + w * 2 + (l >> 5);
    int prow = ((p & ~3) ^ swz) + (p & 3);
    Pack8 pk;
#pragma unroll
    for (int r = 0; r < 8; ++r) pk.h[r] = lds[(o0 + r) * 72 + prow];
    *reinterpret_cast<uint4*>(dst + ((size_t)panel * 64 + p) * NO + o0) = pk.v;
  }
}

__device__ __forceinline__ void fma4h(float acc[4], float w, uint2 v) {
  __half2 h0 = *reinterpret_cast<__half2*>(&v.x);
  __half2 h1 = *reinterpret_cast<__half2*>(&v.y);
  float2 f0 = __half22float2(h0);
  float2 f1 = __half22float2(h1);
  acc[0] = fmaf(w, f0.x, acc[0]);
  acc[1] = fmaf(w, f0.y, acc[1]);
  acc[2] = fmaf(w, f1.x, acc[2]);
  acc[3] = fmaf(w, f1.y, acc[3]);
}

// ---- K2: persistent XCD-phased gather -> partials ----
__global__ __launch_bounds__(128, 4) void lmkan_gather6(
    const float* __restrict__ x, const float* __restrict__ scale,
    const float* __restrict__ biasp, const __half* __restrict__ fpt,
    float* __restrict__ part) {
  const int xcd = blockIdx.x & 7;    // p-range owner: p in [8*xcd, 8*xcd+8)
  const int m   = blockIdx.x >> 3;   // 0..255: b chunk [16m, 16m+16)
  const int t = threadIdx.x;         // 0..127
  const int w = t >> 6;              // wave 0/1: b-locals [8w, 8w+8)
  const int l = t & 63;              // lane owns o = 4l..4l+3

  __shared__ float borders[66];
  __shared__ int jb[16];             // element base of (panel(i,j), p, o=0)
  __shared__ float4 w4[16];          // {w00, w01, w10, w11}

  borders_init(borders, t);
  __syncthreads();

  float acc[8][4] = {};
  const int loff = 4 * l;

#pragma unroll
  for (int ph = 0; ph < 8; ++ph) {
    const int p = 8 * xcd + ph;
    if (t < 16) {
      const int b = m * 16 + t;
      float x1 = x[(size_t)(2 * p) * NB + b]     * scale[2 * p]     + biasp[2 * p];
      float x2 = x[(size_t)(2 * p + 1) * NB + b] * scale[2 * p + 1] + biasp[2 * p + 1];
      const float lo = borders[0];
      const float hi = borders[64] - 1e-6f;
      x1 = fminf(fmaxf(x1, lo), hi);
      x2 = fminf(fmaxf(x2, lo), hi);
      int i = bsearch65(borders, x1);
      int j = bsearch65(borders, x2);
      float t1 = (x1 - borders[i]) / (borders[i + 1] - borders[i]);
      float t2 = (x2 - borders[j]) / (borders[j + 1] - borders[j]);
      jb[t] = ((i * NG + j) * 64 + p) * NO;
      w4[t] = make_float4((1.0f - t1) * (1.0f - t2),  // (i,   j)  : +0
                          (1.0f - t1) * t2,           // (i,   j+1): +PANEL
                          t1 * (1.0f - t2),           // (i+1, j)  : +65*PANEL
                          t1 * t2);                   // (i+1, j+1): +66*PANEL
    }
    __syncthreads();
#pragma unroll
    for (int bb = 0; bb < 8; ++bb) {
      const int bl = w * 8 + bb;
      const float4 wv = w4[bl];
      const __half* q = fpt + jb[bl] + loff;
      uint2 vA = *reinterpret_cast<const uint2*>(q);
      uint2 vB = *reinterpret_cast<const uint2*>(q + PANEL);
      uint2 vC = *reinterpret_cast<const uint2*>(q + 65 * PANEL);
      uint2 vD = *reinterpret_cast<const uint2*>(q + 66 * PANEL);
      fma4h(acc[bb], wv.x, vA);
      fma4h(acc[bb], wv.y, vB);
      fma4h(acc[bb], wv.z, vC);
      fma4h(acc[bb], wv.w, vD);
    }
    __syncthreads();   // protect jb/w4 before next phase rewrites them
  }

  // write partials: part[b][xcd][o], 1KB contiguous per b
#pragma unroll
  for (int bb = 0; bb < 8; ++bb) {
    const int b = m * 16 + w * 8 + bb;
    *reinterpret_cast<float4*>(&part[((size_t)b * 8 + xcd) * NO + loff]) =
        make_float4(acc[bb][0], acc[bb][1], acc[bb][2], acc[bb][3]);
  }
}

// ---- K3: out = relu(W@x + bias) + wlm * sum_k part ----
__global__ __launch_bounds__(256) void lmkan_linear2(
    const float* __restrict__ x, const float* __restrict__ W,
    const float* __restrict__ bias_l, const int* __restrict__ relu_p,
    const float* __restrict__ wlm_p, const float* __restrict__ part,
    float* __restrict__ out) {
  const int b0 = blockIdx.x * 32;
  const int t = threadIdx.x;          // = output row o
  __shared__ __align__(16) float xs[32 * 132];

#pragma unroll
  for (int k = 0; k < 16; ++k) {
    int idx = t + 256 * k;
    int d = idx >> 5, bb = idx & 31;
    xs[bb * 132 + d] = x[(size_t)d * NB + b0 + bb];
  }
  __syncthreads();

  float acc[32];
#pragma unroll
  for (int bb = 0; bb < 32; ++bb) acc[bb] = 0.0f;

  const float4* W4 = reinterpret_cast<const float4*>(W + (size_t)t * ND);
#pragma unroll 8
  for (int d4 = 0; d4 < 32; ++d4) {
    float4 wv = W4[d4];
#pragma unroll
    for (int bb = 0; bb < 32; ++bb) {
      float4 xv = *reinterpret_cast<const float4*>(&xs[bb * 132 + d4 * 4]);
      acc[bb] = fmaf(wv.x, xv.x, acc[bb]);
      acc[bb] = fmaf(wv.y, xv.y, acc[bb]);
      acc[bb] = fmaf(wv.z, xv.z, acc[bb]);
      acc[bb] = fmaf(wv.w, xv.w, acc[bb]);
    }
  }

  const float bias = bias_l[t];
  const int rl = relu_p[0];
  const float wlm = wlm_p[0];
  float* orow = out + (size_t)t * NB + b0;
#pragma unroll 4
  for (int bb = 0; bb < 32; ++bb) {
    float lmsum = 0.0f;
    const float* pr = part + ((size_t)(b0 + bb) * 8) * NO + t;  // lanes coalesced
#pragma unroll
    for (int k = 0; k < 8; ++k) lmsum += pr[k * NO];
    float v = acc[bb] + bias;
    if (rl) v = fmaxf(v, 0.0f);
    orow[bb] = v + wlm * lmsum;
  }
}

// ---- Fallback: direct fp32 gather, fused linear (exact, slow) ----
__global__ __launch_bounds__(64) void lmkan_gather_direct(
    const float* __restrict__ x, const float* __restrict__ scale,
    const float* __restrict__ biasp, const float* __restrict__ W,
    const float* __restrict__ bias_l, const float* __restrict__ wlm_p,
    const int* __restrict__ relu_p, const float* __restrict__ fp,
    float* __restrict__ out) {
  const int b = blockIdx.x;
  const int t = threadIdx.x;

  __shared__ float borders[66];
  __shared__ __align__(16) float xcol[ND];
  __shared__ int pbase[NP];
  __shared__ float4 pw[NP];

  for (int k = t; k < 65; k += 64) {
    float pk = fminf(fmaxf((float)k * (1.0f / 64.0f), 0.0078125f), 0.9921875f);
    borders[k] = 1.41421356237309515f * erfinvf(2.0f * pk - 1.0f);
  }
  xcol[t]      = x[(size_t)t * NB + b];
  xcol[t + 64] = x[(size_t)(t + 64) * NB + b];
  __syncthreads();

  {
    const int p = t;
    float x1 = xcol[2 * p]     * scale[2 * p]     + biasp[2 * p];
    float x2 = xcol[2 * p + 1] * scale[2 * p + 1] + biasp[2 * p + 1];
    const float lo = borders[0];
    const float hi = borders[64] - 1e-6f;
    x1 = fminf(fmaxf(x1, lo), hi);
    x2 = fminf(fmaxf(x2, lo), hi);
    int i = bsearch65(borders, x1);
    int j = bsearch65(borders, x2);
    float t1 = (x1 - borders[i]) / (borders[i + 1] - borders[i]);
    float t2 = (x2 - borders[j]) / (borders[j + 1] - borders[j]);
    pbase[p] = i * NG + j;
    pw[p] = make_float4((1.0f - t1) * (1.0f - t2), t1 * (1.0f - t2),
                        (1.0f - t1) * t2, t1 * t2);
  }
  __syncthreads();

  float acc[4] = {0, 0, 0, 0};
  for (int p = 0; p < NP; ++p) {
    int base = pbase[p];
    float4 wv = pw[p];
#pragma unroll
    for (int k = 0; k < 4; ++k) {
      size_t r = ((size_t)base * NO + (4 * t + k)) * NP + p;
      acc[k] += wv.x * fp[r] + wv.y * fp[r + 65 * PANEL] +
                wv.z * fp[r + PANEL] + wv.w * fp[r + 66 * PANEL];
    }
  }

  const float wlm = wlm_p[0];
  const int rl = relu_p[0];
  const float4* xc4 = reinterpret_cast<const float4*>(xcol);
#pragma unroll
  for (int k = 0; k < 4; ++k) {
    const int o = 4 * t + k;
    const float4* wr = reinterpret_cast<const float4*>(W + (size_t)o * ND);
    float s = 0.0f;
#pragma unroll 8
    for (int d4 = 0; d4 < ND / 4; ++d4) {
      float4 wv = wr[d4];
      float4 xv = xc4[d4];
      s = fmaf(wv.x, xv.x, s);
      s = fmaf(wv.y, xv.y, s);
      s = fmaf(wv.z, xv.z, s);
      s = fmaf(wv.w, xv.w, s);
    }
    s += bias_l[o];
    if (rl) s = fmaxf(s, 0.0f);
    out[(size_t)o * NB + b] = s + wlm * acc[k];
  }
}

extern "C" void kernel_launch(void* const* d_in, const int* in_sizes, int n_in,
                              void* d_out, int out_size, void* d_ws, size_t ws_size,
                              hipStream_t stream) {
  const float* x     = reinterpret_cast<const float*>(d_in[0]);
  const float* wlm   = reinterpret_cast<const float*>(d_in[1]);
  const int*   relu  = reinterpret_cast<const int*>(d_in[2]);
  const float* fp    = reinterpret_cast<const float*>(d_in[3]);
  const float* scale = reinterpret_cast<const float*>(d_in[4]);
  const float* biasp = reinterpret_cast<const float*>(d_in[5]);
  const float* W     = reinterpret_cast<const float*>(d_in[6]);
  const float* bl    = reinterpret_cast<const float*>(d_in[7]);
  float* out = reinterpret_cast<float*>(d_out);

  const size_t need = FPT_BYTES + PART_FLOATS * sizeof(float);  // ~164 MiB
  if (ws_size >= need) {
    __half* fpt = reinterpret_cast<__half*>(d_ws);
    float* part = reinterpret_cast<float*>(
        reinterpret_cast<char*>(d_ws) + FPT_BYTES);
    lmkan_transpose3<<<NG * NG, 256, 0, stream>>>(fp, fpt);
    lmkan_gather6<<<2048, 128, 0, stream>>>(x, scale, biasp, fpt, part);
    lmkan_linear2<<<NB / 32, 256, 0, stream>>>(x, W, bl, relu, wlm, part, out);
  } else {
    lmkan_gather_direct<<<NB, 64, 0, stream>>>(x, scale, biasp, W, bl, wlm, relu, fp, out);
  }
}